// Round 8
// baseline (940.064 us; speedup 1.0000x reference)
//
// Round 8: identical to round 7 except __launch_bounds__(512, 3) on kv_attn.
// Theory: (512,4)'s 128-unified-reg cap spilled the persistent accumulators
// (out_acc/denom/qn ~20 dwords) once per sub-chunk -> 173 MB WRITE_SIZE of
// scratch RMW. 3 waves/EU -> ~170-reg cap fits peak live set -> no spill.
#include <hip/hip_runtime.h>
#include <hip/hip_bf16.h>

#define SOFTCAP_ 50.0f
#define EPS_ 1e-6f

typedef __attribute__((ext_vector_type(8))) short bf16x8;
typedef __attribute__((ext_vector_type(4))) float f32x4;

__device__ __forceinline__ unsigned short f2bf(float f) {
    unsigned u = __float_as_uint(f);
    u += 0x7FFFu + ((u >> 16) & 1u);
    return (unsigned short)(u >> 16);
}

// ---------------- Wkv -> bf16 fragment-layout swizzle ----------------
// layout: [kb(32)][nb(32)][lane(64)][j(8)]  value = W'[kb*32+(l>>4)*8+j][nb*16+(l&15)]
// n<256 -> Wk col n ; n>=256 -> Wv col n-256
__global__ void wkv_swizzle(const float* __restrict__ Wk, const float* __restrict__ Wv,
                            unsigned short* __restrict__ wkv) {
    int tid = blockIdx.x * 256 + threadIdx.x;   // 0..65535
    int l = tid & 63;
    int nb = (tid >> 6) & 31;
    int kb = tid >> 11;
    int n = nb * 16 + (l & 15);
    int kbase = kb * 32 + ((l >> 4) << 3);
    const float* src = (n < 256) ? (Wk + n) : (Wv + (n - 256));
    unsigned short r[8];
#pragma unroll
    for (int j = 0; j < 8; ++j) r[j] = f2bf(src[(size_t)(kbase + j) * 256]);
    uint4 o;
    o.x = (unsigned)r[0] | ((unsigned)r[1] << 16);
    o.y = (unsigned)r[2] | ((unsigned)r[3] << 16);
    o.z = (unsigned)r[4] | ((unsigned)r[5] << 16);
    o.w = (unsigned)r[6] | ((unsigned)r[7] << 16);
    *(uint4*)(wkv + (size_t)tid * 8) = o;
}

// ---------------- Q projection + RMSNorm ----------------
__global__ __launch_bounds__(256) void qproj_kernel(
    const float* __restrict__ agent, const float* __restrict__ Wq,
    const float* __restrict__ q_gamma, float* __restrict__ ws_q)
{
    __shared__ float srows[8][1024];
    int cg = blockIdx.x, rg = blockIdx.y;
    int t = threadIdx.x;
#pragma unroll
    for (int j = 0; j < 8; ++j) {
        int f = j * 256 + t;          // float4 index 0..2047
        int row = f >> 8, c4 = f & 255;
        *(float4*)&srows[row][c4 * 4] =
            *(const float4*)(agent + (size_t)(rg * 8 + row) * 1024 + c4 * 4);
    }
    __syncthreads();
    int c = cg * 64 + (t & 63);
    int rq = t >> 6;                  // 2 rows per thread
    float acc0 = 0.f, acc1 = 0.f;
    for (int k = 0; k < 1024; k += 4) {
        float w0 = Wq[(size_t)(k + 0) * 1024 + c];
        float w1 = Wq[(size_t)(k + 1) * 1024 + c];
        float w2 = Wq[(size_t)(k + 2) * 1024 + c];
        float w3 = Wq[(size_t)(k + 3) * 1024 + c];
        float4 a0 = *(const float4*)&srows[rq * 2][k];
        float4 a1 = *(const float4*)&srows[rq * 2 + 1][k];
        acc0 += a0.x * w0 + a0.y * w1 + a0.z * w2 + a0.w * w3;
        acc1 += a1.x * w0 + a1.y * w1 + a1.z * w2 + a1.w * w3;
    }
    float g = q_gamma[t & 63];
    float ss0 = acc0 * acc0, ss1 = acc1 * acc1;
#pragma unroll
    for (int d = 1; d < 64; d <<= 1) { ss0 += __shfl_xor(ss0, d); ss1 += __shfl_xor(ss1, d); }
    float rs0 = rsqrtf(ss0 * (1.0f / 64.0f) + EPS_);
    float rs1 = rsqrtf(ss1 * (1.0f / 64.0f) + EPS_);
    ws_q[(size_t)(rg * 8 + rq * 2 + 0) * 1024 + c] = acc0 * rs0 * g;
    ws_q[(size_t)(rg * 8 + rq * 2 + 1) * 1024 + c] = acc1 * rs1 * g;
}

// ---------------- Fused KV projection + attention (K/V wave-specialized) ----------------
// grid 512 = bt, 512 threads = 8 waves. w<4: K-wave for kv-head w; w>=4: V-wave.
// 8 sub-chunks of 32 s-rows; acc[2][4] (32 regs) per wave.
// K-waves compute RMSNorm+scores+softcap+exp, hand p to V-waves via p_lds (barrier);
// V-waves accumulate PV. Denominators combined in-block at the end.
__global__ __launch_bounds__(512, 3) void kv_attn_kernel(
    const float* __restrict__ z, const unsigned short* __restrict__ wkv,
    const float* __restrict__ ws_q, const float* __restrict__ k_gamma,
    float* __restrict__ ws_att)
{
    __shared__ __align__(16) unsigned short zlds[32 * 256];   // 16 KB, XOR-swizzled bf16
    __shared__ float p_lds[16 * 32];                          // 2 KB
    __shared__ float den_lds[16];
    const int bt = blockIdx.x;
    const int tid = threadIdx.x;
    const int w = tid >> 6;                // 0..7
    const bool isK = (w < 4);
    const int kvh = w & 3;                 // kv head 0..3
    const int nbase = isK ? (kvh * 4) : (16 + kvh * 4);
    const int l = tid & 63, l15 = l & 15, lg = l >> 4;

    float qn[4][4], kgm[4];                // K-waves only (live in their path)
    if (isK) {
#pragma unroll
        for (int g = 0; g < 4; ++g)
#pragma unroll
            for (int ni = 0; ni < 4; ++ni)
                qn[g][ni] = ws_q[(size_t)bt * 1024 + (kvh * 4 + g) * 64 + ni * 16 + l15];
#pragma unroll
        for (int ni = 0; ni < 4; ++ni) kgm[ni] = k_gamma[ni * 16 + l15];
    }

    float out_acc[4][4] = {};   // V-waves
    float denom[4] = {};        // K-waves

    for (int sc = 0; sc < 8; ++sc) {       // 8 sub-chunks of 32 s-rows
        f32x4 acc[2][4];
#pragma unroll
        for (int mi = 0; mi < 2; ++mi)
#pragma unroll
            for (int ni = 0; ni < 4; ++ni) acc[mi][ni] = (f32x4){0.f, 0.f, 0.f, 0.f};

        for (int sl = 0; sl < 4; ++sl) {   // k-slices of 256
            __syncthreads();               // prior reads of zlds (and p_lds) done
#pragma unroll
            for (int j = 0; j < 4; ++j) {  // stage 32x256 fp32 -> bf16
                int f = j * 512 + tid;     // float4 idx 0..2047
                int row = f >> 6, c4 = f & 63;
                float4 v4 = *(const float4*)(z + (size_t)(bt * 256 + sc * 32 + row) * 1024
                                               + sl * 256 + c4 * 4);
                unsigned lo = (unsigned)f2bf(v4.x) | ((unsigned)f2bf(v4.y) << 16);
                unsigned hi = (unsigned)f2bf(v4.z) | ((unsigned)f2bf(v4.w) << 16);
                int byteoff = ((row * 512) + c4 * 8) ^ ((row & 7) << 4);
                *(uint2*)((char*)zlds + byteoff) = (uint2){lo, hi};
            }
            __syncthreads();               // stage visible
#pragma unroll
            for (int ksl = 0; ksl < 8; ++ksl) {
                const int kb = sl * 8 + ksl;
                int boff0 = ((l15 * 512) + ksl * 64 + lg * 16) ^ ((l15 & 7) << 4);
                bf16x8 a0 = *(const bf16x8*)((const char*)zlds + boff0);
                bf16x8 a1 = *(const bf16x8*)((const char*)zlds + boff0 + 8192); // row+16: same swizzle
                bf16x8 b[4];
#pragma unroll
                for (int ni = 0; ni < 4; ++ni)
                    b[ni] = *(const bf16x8*)(wkv + ((size_t)(kb * 32 + nbase + ni) * 64 + l) * 8);
#pragma unroll
                for (int ni = 0; ni < 4; ++ni) {
                    acc[0][ni] = __builtin_amdgcn_mfma_f32_16x16x32_bf16(a0, b[ni], acc[0][ni], 0, 0, 0);
                    acc[1][ni] = __builtin_amdgcn_mfma_f32_16x16x32_bf16(a1, b[ni], acc[1][ni], 0, 0, 0);
                }
            }
        }
        // ---- epilogue: K-waves make p; V-waves consume after barrier ----
        if (isK) {
#pragma unroll
            for (int mi = 0; mi < 2; ++mi) {
#pragma unroll
                for (int r = 0; r < 4; ++r) {
                    float k0 = acc[mi][0][r], k1 = acc[mi][1][r], k2 = acc[mi][2][r], k3 = acc[mi][3][r];
                    float ss = k0 * k0 + k1 * k1 + k2 * k2 + k3 * k3;
                    ss += __shfl_xor(ss, 1); ss += __shfl_xor(ss, 2);
                    ss += __shfl_xor(ss, 4); ss += __shfl_xor(ss, 8);
                    float rs = rsqrtf(ss * (1.0f / 64.0f) + EPS_);
                    k0 *= rs * kgm[0]; k1 *= rs * kgm[1]; k2 *= rs * kgm[2]; k3 *= rs * kgm[3];
#pragma unroll
                    for (int g = 0; g < 4; ++g) {
                        float sp = qn[g][0] * k0 + qn[g][1] * k1 + qn[g][2] * k2 + qn[g][3] * k3;
                        sp += __shfl_xor(sp, 1); sp += __shfl_xor(sp, 2);
                        sp += __shfl_xor(sp, 4); sp += __shfl_xor(sp, 8);
                        float scv = sp * 0.125f;                    // * hd^-0.5
                        float e2 = __expf(scv * (2.0f / SOFTCAP_));
                        float th = 1.0f - 2.0f / (e2 + 1.0f);       // tanh
                        float p = __expf(SOFTCAP_ * th);            // |capped|<=50, fp32-safe
                        denom[g] += p;
                        if (l15 == g)
                            p_lds[(kvh * 4 + g) * 32 + mi * 16 + lg * 4 + r] = p;
                    }
                }
            }
        }
        __syncthreads();                   // p visible to V-waves
        if (!isK) {
#pragma unroll
            for (int mi = 0; mi < 2; ++mi)
#pragma unroll
                for (int r = 0; r < 4; ++r) {
                    int row = mi * 16 + lg * 4 + r;
#pragma unroll
                    for (int g = 0; g < 4; ++g) {
                        float p = p_lds[(kvh * 4 + g) * 32 + row];
                        out_acc[g][0] += p * acc[mi][0][r];
                        out_acc[g][1] += p * acc[mi][1][r];
                        out_acc[g][2] += p * acc[mi][2][r];
                        out_acc[g][3] += p * acc[mi][3][r];
                    }
                }
        }
        // next sc's first stage-barrier orders V's p_lds reads before K's next writes
    }
    // ---- finalize: K-waves publish denominators; V-waves normalize + write ----
    if (isK) {
#pragma unroll
        for (int g = 0; g < 4; ++g) {
            float d = denom[g];
            d += __shfl_xor(d, 16); d += __shfl_xor(d, 32);
            if (l == g) den_lds[kvh * 4 + g] = d;
        }
    }
    __syncthreads();
    if (!isK) {
#pragma unroll
        for (int g = 0; g < 4; ++g) {
            float inv = 1.0f / den_lds[kvh * 4 + g];
#pragma unroll
            for (int ni = 0; ni < 4; ++ni) {
                float o = out_acc[g][ni];
                o += __shfl_xor(o, 16); o += __shfl_xor(o, 32);
                if (lg == 0)
                    ws_att[(size_t)bt * 1024 + (kvh * 4 + g) * 64 + ni * 16 + l15] = o * inv;
            }
        }
    }
}

// ---------------- Output projection ----------------
__global__ __launch_bounds__(256) void oproj_kernel(
    const float* __restrict__ att, const float* __restrict__ Wo,
    float* __restrict__ out)
{
    __shared__ float srows[8][1024];
    int cg = blockIdx.x, rg = blockIdx.y;
    int t = threadIdx.x;
#pragma unroll
    for (int j = 0; j < 8; ++j) {
        int f = j * 256 + t;
        int row = f >> 8, c4 = f & 255;
        *(float4*)&srows[row][c4 * 4] =
            *(const float4*)(att + (size_t)(rg * 8 + row) * 1024 + c4 * 4);
    }
    __syncthreads();
    int c = cg * 64 + (t & 63);
    int rq = t >> 6;
    float acc0 = 0.f, acc1 = 0.f;
    for (int k = 0; k < 1024; k += 4) {
        float w0 = Wo[(size_t)(k + 0) * 1024 + c];
        float w1 = Wo[(size_t)(k + 1) * 1024 + c];
        float w2 = Wo[(size_t)(k + 2) * 1024 + c];
        float w3 = Wo[(size_t)(k + 3) * 1024 + c];
        float4 a0 = *(const float4*)&srows[rq * 2][k];
        float4 a1 = *(const float4*)&srows[rq * 2 + 1][k];
        acc0 += a0.x * w0 + a0.y * w1 + a0.z * w2 + a0.w * w3;
        acc1 += a1.x * w0 + a1.y * w1 + a1.z * w2 + a1.w * w3;
    }
    out[(size_t)(rg * 8 + rq * 2 + 0) * 1024 + c] = acc0;
    out[(size_t)(rg * 8 + rq * 2 + 1) * 1024 + c] = acc1;
}

extern "C" void kernel_launch(void* const* d_in, const int* in_sizes, int n_in,
                              void* d_out, int out_size, void* d_ws, size_t ws_size,
                              hipStream_t stream) {
    const float* agent = (const float*)d_in[0];
    const float* z     = (const float*)d_in[1];
    const float* Wq    = (const float*)d_in[2];
    const float* Wk    = (const float*)d_in[3];
    const float* Wv    = (const float*)d_in[4];
    const float* Wo    = (const float*)d_in[5];
    const float* qg    = (const float*)d_in[6];
    const float* kg    = (const float*)d_in[7];
    float* out = (float*)d_out;

    char* ws = (char*)d_ws;
    float* ws_q   = (float*)ws;                          // 2 MB
    float* ws_att = (float*)(ws + (2u << 20));           // 2 MB
    unsigned short* ws_wkv = (unsigned short*)(ws + (4u << 20)); // 1 MB  (total 5 MB, proven)

    hipLaunchKernelGGL(wkv_swizzle, dim3(256), dim3(256), 0, stream, Wk, Wv, ws_wkv);
    hipLaunchKernelGGL(qproj_kernel, dim3(16, 64), dim3(256), 0, stream, agent, Wq, qg, ws_q);
    hipLaunchKernelGGL(kv_attn_kernel, dim3(512), dim3(512), 0, stream, z, ws_wkv, ws_q, kg, ws_att);
    hipLaunchKernelGGL(oproj_kernel, dim3(16, 64), dim3(256), 0, stream, ws_att, Wo, out);
}

// Round 9
// 744.473 us; speedup vs baseline: 1.2627x; 1.2627x over previous
//
// Round 9: PZ-trick — out = (P·Z)·Wv/den (V linear: no V-projection MFMA).
// K-waves (0-3): z·Wk scores, r7-proven math. Y-waves (4-7): Y += p·z via MFMA.
// zlds[32][1024] staged once per sub-chunk (3 barriers vs r7's 9). No spills at (512,4).
#include <hip/hip_runtime.h>
#include <hip/hip_bf16.h>

#define SOFTCAP_ 50.0f
#define EPS_ 1e-6f

typedef __attribute__((ext_vector_type(8))) short bf16x8;
typedef __attribute__((ext_vector_type(4))) float f32x4;

__device__ __forceinline__ unsigned short f2bf(float f) {
    unsigned u = __float_as_uint(f);
    u += 0x7FFFu + ((u >> 16) & 1u);
    return (unsigned short)(u >> 16);
}

// ---------------- Wkv -> bf16 fragment-layout swizzle (K half used; V half spare) ----
__global__ void wkv_swizzle(const float* __restrict__ Wk, const float* __restrict__ Wv,
                            unsigned short* __restrict__ wkv) {
    int tid = blockIdx.x * 256 + threadIdx.x;   // 0..65535
    int l = tid & 63;
    int nb = (tid >> 6) & 31;
    int kb = tid >> 11;
    int n = nb * 16 + (l & 15);
    int kbase = kb * 32 + ((l >> 4) << 3);
    const float* src = (n < 256) ? (Wk + n) : (Wv + (n - 256));
    unsigned short r[8];
#pragma unroll
    for (int j = 0; j < 8; ++j) r[j] = f2bf(src[(size_t)(kbase + j) * 256]);
    uint4 o;
    o.x = (unsigned)r[0] | ((unsigned)r[1] << 16);
    o.y = (unsigned)r[2] | ((unsigned)r[3] << 16);
    o.z = (unsigned)r[4] | ((unsigned)r[5] << 16);
    o.w = (unsigned)r[6] | ((unsigned)r[7] << 16);
    *(uint4*)(wkv + (size_t)tid * 8) = o;
}

// ---------------- Q projection + RMSNorm ----------------
__global__ __launch_bounds__(256) void qproj_kernel(
    const float* __restrict__ agent, const float* __restrict__ Wq,
    const float* __restrict__ q_gamma, float* __restrict__ ws_q)
{
    __shared__ float srows[8][1024];
    int cg = blockIdx.x, rg = blockIdx.y;
    int t = threadIdx.x;
#pragma unroll
    for (int j = 0; j < 8; ++j) {
        int f = j * 256 + t;
        int row = f >> 8, c4 = f & 255;
        *(float4*)&srows[row][c4 * 4] =
            *(const float4*)(agent + (size_t)(rg * 8 + row) * 1024 + c4 * 4);
    }
    __syncthreads();
    int c = cg * 64 + (t & 63);
    int rq = t >> 6;
    float acc0 = 0.f, acc1 = 0.f;
    for (int k = 0; k < 1024; k += 4) {
        float w0 = Wq[(size_t)(k + 0) * 1024 + c];
        float w1 = Wq[(size_t)(k + 1) * 1024 + c];
        float w2 = Wq[(size_t)(k + 2) * 1024 + c];
        float w3 = Wq[(size_t)(k + 3) * 1024 + c];
        float4 a0 = *(const float4*)&srows[rq * 2][k];
        float4 a1 = *(const float4*)&srows[rq * 2 + 1][k];
        acc0 += a0.x * w0 + a0.y * w1 + a0.z * w2 + a0.w * w3;
        acc1 += a1.x * w0 + a1.y * w1 + a1.z * w2 + a1.w * w3;
    }
    float g = q_gamma[t & 63];
    float ss0 = acc0 * acc0, ss1 = acc1 * acc1;
#pragma unroll
    for (int d = 1; d < 64; d <<= 1) { ss0 += __shfl_xor(ss0, d); ss1 += __shfl_xor(ss1, d); }
    float rs0 = rsqrtf(ss0 * (1.0f / 64.0f) + EPS_);
    float rs1 = rsqrtf(ss1 * (1.0f / 64.0f) + EPS_);
    ws_q[(size_t)(rg * 8 + rq * 2 + 0) * 1024 + c] = acc0 * rs0 * g;
    ws_q[(size_t)(rg * 8 + rq * 2 + 1) * 1024 + c] = acc1 * rs1 * g;
}

// ---------------- Fused K-proj + attention + PZ accumulation ----------------
// grid 512 = bt, 512 thr = 8 waves. Waves 0-3: K-scores for kv-head w (32 rows/sub-chunk,
// acc[2][4]). Waves 4-7: Y[16q][256 cols] += P·Z via MFMA. 8 sub-chunks of 32 s-rows.
// Epilogue: Y->LDS (union with zlds), mini-GEMM x Wv / den -> ws_att.
__global__ __launch_bounds__(512, 4) void kv_attn_kernel(
    const float* __restrict__ z, const unsigned short* __restrict__ wkv,
    const float* __restrict__ ws_q, const float* __restrict__ k_gamma,
    const float* __restrict__ Wv, float* __restrict__ ws_att)
{
    __shared__ __align__(16) char smem[65792];         // union: zlds bf16[32][1024] / y_lds f32[16][1028]
    __shared__ __align__(16) unsigned short p_lds[16][40];  // bf16 p, padded rows
    __shared__ float den_lds[16];
    unsigned short* zlds = (unsigned short*)smem;
    float* y_lds = (float*)smem;                       // [16][1028]
    const int bt = blockIdx.x;
    const int tid = threadIdx.x;
    const int w = tid >> 6;
    const bool isK = (w < 4);
    const int h = w & 3;                               // K: kv-head; Y: col-group
    const int l = tid & 63, l15 = l & 15, lg = l >> 4;

    float qn[4][4], kgm[4];
    float denom[4] = {};
    if (isK) {
#pragma unroll
        for (int g = 0; g < 4; ++g)
#pragma unroll
            for (int ni = 0; ni < 4; ++ni)
                qn[g][ni] = ws_q[(size_t)bt * 1024 + (h * 4 + g) * 64 + ni * 16 + l15];
#pragma unroll
        for (int ni = 0; ni < 4; ++ni) kgm[ni] = k_gamma[ni * 16 + l15];
    }
    f32x4 Y[16];
#pragma unroll
    for (int t = 0; t < 16; ++t) Y[t] = (f32x4){0.f, 0.f, 0.f, 0.f};

    for (int sc = 0; sc < 8; ++sc) {
        __syncthreads();                // prev Y-phase reads of zlds done
        // ---- stage 32 rows x 1024 cols fp32 -> bf16 (16 float4/thread, 4 batches) ----
#pragma unroll
        for (int b = 0; b < 4; ++b) {
            float4 v[4];
#pragma unroll
            for (int i = 0; i < 4; ++i) {
                int f = (b * 4 + i) * 512 + tid;
                int row = f >> 8, c4 = f & 255;
                v[i] = *(const float4*)(z + (size_t)(bt * 256 + sc * 32 + row) * 1024 + c4 * 4);
            }
#pragma unroll
            for (int i = 0; i < 4; ++i) {
                int f = (b * 4 + i) * 512 + tid;
                int row = f >> 8, c4 = f & 255;
                unsigned lo = (unsigned)f2bf(v[i].x) | ((unsigned)f2bf(v[i].y) << 16);
                unsigned hi = (unsigned)f2bf(v[i].z) | ((unsigned)f2bf(v[i].w) << 16);
                int off = (row * 2048 + c4 * 8) ^ ((row & 7) << 4);
                *(uint2*)(smem + off) = (uint2){lo, hi};
            }
        }
        __syncthreads();                // stage visible
        if (isK) {
            f32x4 acc[2][4];
#pragma unroll
            for (int mi = 0; mi < 2; ++mi)
#pragma unroll
                for (int ni = 0; ni < 4; ++ni) acc[mi][ni] = (f32x4){0.f, 0.f, 0.f, 0.f};
            for (int kb = 0; kb < 32; ++kb) {
                int o0 = (l15 * 2048 + kb * 64 + lg * 16) ^ ((l15 & 7) << 4);
                bf16x8 a0 = *(const bf16x8*)(smem + o0);
                bf16x8 a1 = *(const bf16x8*)(smem + o0 + 32768);   // row+16, same XOR
                bf16x8 b[4];
#pragma unroll
                for (int ni = 0; ni < 4; ++ni)
                    b[ni] = *(const bf16x8*)(wkv + ((size_t)(kb * 32 + h * 4 + ni) * 64 + l) * 8);
#pragma unroll
                for (int ni = 0; ni < 4; ++ni) {
                    acc[0][ni] = __builtin_amdgcn_mfma_f32_16x16x32_bf16(a0, b[ni], acc[0][ni], 0, 0, 0);
                    acc[1][ni] = __builtin_amdgcn_mfma_f32_16x16x32_bf16(a1, b[ni], acc[1][ni], 0, 0, 0);
                }
            }
            // ---- scores -> p (r7-proven math), write p_lds as bf16 ----
#pragma unroll
            for (int mi = 0; mi < 2; ++mi) {
#pragma unroll
                for (int r = 0; r < 4; ++r) {
                    float k0 = acc[mi][0][r], k1 = acc[mi][1][r], k2 = acc[mi][2][r], k3 = acc[mi][3][r];
                    float ss = k0 * k0 + k1 * k1 + k2 * k2 + k3 * k3;
                    ss += __shfl_xor(ss, 1); ss += __shfl_xor(ss, 2);
                    ss += __shfl_xor(ss, 4); ss += __shfl_xor(ss, 8);
                    float rs = rsqrtf(ss * (1.0f / 64.0f) + EPS_);
                    k0 *= rs * kgm[0]; k1 *= rs * kgm[1]; k2 *= rs * kgm[2]; k3 *= rs * kgm[3];
#pragma unroll
                    for (int g = 0; g < 4; ++g) {
                        float sp = qn[g][0] * k0 + qn[g][1] * k1 + qn[g][2] * k2 + qn[g][3] * k3;
                        sp += __shfl_xor(sp, 1); sp += __shfl_xor(sp, 2);
                        sp += __shfl_xor(sp, 4); sp += __shfl_xor(sp, 8);
                        float scv = sp * 0.125f;
                        float e2 = __expf(scv * (2.0f / SOFTCAP_));
                        float th = 1.0f - 2.0f / (e2 + 1.0f);
                        float p = __expf(SOFTCAP_ * th);
                        denom[g] += p;
                        if (l15 == g)
                            p_lds[h * 4 + g][mi * 16 + lg * 4 + r] = f2bf(p);
                    }
                }
            }
        }
        __syncthreads();                // p ready
        if (!isK) {
            // A-frag: p[16q x 32s]; lane: m=l15(q), k=lg*8+j(s)
            bf16x8 ap = *(const bf16x8*)((const char*)p_lds + l15 * 80 + lg * 16);
#pragma unroll
            for (int t = 0; t < 16; ++t) {
                int c0 = h * 256 + t * 16;
                unsigned short g8[8];
#pragma unroll
                for (int jj = 0; jj < 8; ++jj) {
                    int s = lg * 8 + jj;
                    int off = (s * 2048 + (c0 + l15) * 2) ^ (jj << 4);
                    g8[jj] = *(const unsigned short*)(smem + off);
                }
                bf16x8 bz = {(short)g8[0], (short)g8[1], (short)g8[2], (short)g8[3],
                             (short)g8[4], (short)g8[5], (short)g8[6], (short)g8[7]};
                Y[t] = __builtin_amdgcn_mfma_f32_16x16x32_bf16(ap, bz, Y[t], 0, 0, 0);
            }
        }
        // loop-top barrier orders Y-phase reads before next stage
    }
    // ---- finalize: denominators, Y -> LDS, mini-GEMM x Wv ----
    if (isK) {
#pragma unroll
        for (int g = 0; g < 4; ++g) {
            float d = denom[g];
            d += __shfl_xor(d, 16); d += __shfl_xor(d, 32);
            if (l == g) den_lds[h * 4 + g] = d;
        }
    }
    __syncthreads();
    if (!isK) {
        // C-layout: q = lg*4 + r, col = c0 + l15  (overwrites zlds region; reads done)
#pragma unroll
        for (int t = 0; t < 16; ++t)
#pragma unroll
            for (int r = 0; r < 4; ++r)
                y_lds[(lg * 4 + r) * 1028 + h * 256 + t * 16 + l15] = Y[t][r];
    }
    __syncthreads();
    if (tid < 256) {
        // out[q][64] = (Y[q]/den[q]) . Wv[:, (q>>2)*64 .. +63]; thread: cb=tid>>6, d=tid&63
        int cb = tid >> 6, d = tid & 63;
        int col = cb * 64 + d;
        float a0 = 0.f, a1 = 0.f, a2 = 0.f, a3 = 0.f;
        const float* y0 = y_lds + (cb * 4 + 0) * 1028;
        const float* y1 = y_lds + (cb * 4 + 1) * 1028;
        const float* y2 = y_lds + (cb * 4 + 2) * 1028;
        const float* y3 = y_lds + (cb * 4 + 3) * 1028;
        for (int k = 0; k < 1024; k += 4) {
            float4 wv;
            wv.x = Wv[(size_t)(k + 0) * 256 + col];
            wv.y = Wv[(size_t)(k + 1) * 256 + col];
            wv.z = Wv[(size_t)(k + 2) * 256 + col];
            wv.w = Wv[(size_t)(k + 3) * 256 + col];
            float4 v0 = *(const float4*)(y0 + k);
            float4 v1 = *(const float4*)(y1 + k);
            float4 v2 = *(const float4*)(y2 + k);
            float4 v3 = *(const float4*)(y3 + k);
            a0 += v0.x * wv.x + v0.y * wv.y + v0.z * wv.z + v0.w * wv.w;
            a1 += v1.x * wv.x + v1.y * wv.y + v1.z * wv.z + v1.w * wv.w;
            a2 += v2.x * wv.x + v2.y * wv.y + v2.z * wv.z + v2.w * wv.w;
            a3 += v3.x * wv.x + v3.y * wv.y + v3.z * wv.z + v3.w * wv.w;
        }
        float* outp = ws_att + (size_t)bt * 1024;
        outp[(cb * 4 + 0) * 64 + d] = a0 / den_lds[cb * 4 + 0];
        outp[(cb * 4 + 1) * 64 + d] = a1 / den_lds[cb * 4 + 1];
        outp[(cb * 4 + 2) * 64 + d] = a2 / den_lds[cb * 4 + 2];
        outp[(cb * 4 + 3) * 64 + d] = a3 / den_lds[cb * 4 + 3];
    }
}

// ---------------- Output projection ----------------
__global__ __launch_bounds__(256) void oproj_kernel(
    const float* __restrict__ att, const float* __restrict__ Wo,
    float* __restrict__ out)
{
    __shared__ float srows[8][1024];
    int cg = blockIdx.x, rg = blockIdx.y;
    int t = threadIdx.x;
#pragma unroll
    for (int j = 0; j < 8; ++j) {
        int f = j * 256 + t;
        int row = f >> 8, c4 = f & 255;
        *(float4*)&srows[row][c4 * 4] =
            *(const float4*)(att + (size_t)(rg * 8 + row) * 1024 + c4 * 4);
    }
    __syncthreads();
    int c = cg * 64 + (t & 63);
    int rq = t >> 6;
    float acc0 = 0.f, acc1 = 0.f;
    for (int k = 0; k < 1024; k += 4) {
        float w0 = Wo[(size_t)(k + 0) * 1024 + c];
        float w1 = Wo[(size_t)(k + 1) * 1024 + c];
        float w2 = Wo[(size_t)(k + 2) * 1024 + c];
        float w3 = Wo[(size_t)(k + 3) * 1024 + c];
        float4 a0 = *(const float4*)&srows[rq * 2][k];
        float4 a1 = *(const float4*)&srows[rq * 2 + 1][k];
        acc0 += a0.x * w0 + a0.y * w1 + a0.z * w2 + a0.w * w3;
        acc1 += a1.x * w0 + a1.y * w1 + a1.z * w2 + a1.w * w3;
    }
    out[(size_t)(rg * 8 + rq * 2 + 0) * 1024 + c] = acc0;
    out[(size_t)(rg * 8 + rq * 2 + 1) * 1024 + c] = acc1;
}

extern "C" void kernel_launch(void* const* d_in, const int* in_sizes, int n_in,
                              void* d_out, int out_size, void* d_ws, size_t ws_size,
                              hipStream_t stream) {
    const float* agent = (const float*)d_in[0];
    const float* z     = (const float*)d_in[1];
    const float* Wq    = (const float*)d_in[2];
    const float* Wk    = (const float*)d_in[3];
    const float* Wv    = (const float*)d_in[4];
    const float* Wo    = (const float*)d_in[5];
    const float* qg    = (const float*)d_in[6];
    const float* kg    = (const float*)d_in[7];
    float* out = (float*)d_out;

    char* ws = (char*)d_ws;
    float* ws_q   = (float*)ws;                          // 2 MB
    float* ws_att = (float*)(ws + (2u << 20));           // 2 MB
    unsigned short* ws_wkv = (unsigned short*)(ws + (4u << 20)); // 1 MB  (5 MB total, proven)

    hipLaunchKernelGGL(wkv_swizzle, dim3(256), dim3(256), 0, stream, Wk, Wv, ws_wkv);
    hipLaunchKernelGGL(qproj_kernel, dim3(16, 64), dim3(256), 0, stream, agent, Wq, qg, ws_q);
    hipLaunchKernelGGL(kv_attn_kernel, dim3(512), dim3(512), 0, stream, z, ws_wkv, ws_q, kg, Wv, ws_att);
    hipLaunchKernelGGL(oproj_kernel, dim3(16, 64), dim3(256), 0, stream, ws_att, Wo, out);
}

// Round 10
// 400.585 us; speedup vs baseline: 2.3467x; 1.8585x over previous
//
// Round 10: in-wave K+V (r6 math, proven) on 256-thread blocks @ (256,3).
// Cap ~170 regs fits the ~155-reg live set (NO spill, unlike r1/r2/r6/r7/r9)
// while 3 independent blocks/CU provide cross-block TLP (unlike r8's 1 block).
#include <hip/hip_runtime.h>
#include <hip/hip_bf16.h>

#define SOFTCAP_ 50.0f
#define EPS_ 1e-6f

typedef __attribute__((ext_vector_type(8))) short bf16x8;
typedef __attribute__((ext_vector_type(4))) float f32x4;

__device__ __forceinline__ unsigned short f2bf(float f) {
    unsigned u = __float_as_uint(f);
    u += 0x7FFFu + ((u >> 16) & 1u);
    return (unsigned short)(u >> 16);
}

// ---------------- Wkv -> bf16 fragment-layout swizzle ----------------
// layout: [kb(32)][nb(32)][lane(64)][j(8)]  value = W'[kb*32+(l>>4)*8+j][nb*16+(l&15)]
// n<256 -> Wk col n ; n>=256 -> Wv col n-256
__global__ void wkv_swizzle(const float* __restrict__ Wk, const float* __restrict__ Wv,
                            unsigned short* __restrict__ wkv) {
    int tid = blockIdx.x * 256 + threadIdx.x;   // 0..65535
    int l = tid & 63;
    int nb = (tid >> 6) & 31;
    int kb = tid >> 11;
    int n = nb * 16 + (l & 15);
    int kbase = kb * 32 + ((l >> 4) << 3);
    const float* src = (n < 256) ? (Wk + n) : (Wv + (n - 256));
    unsigned short r[8];
#pragma unroll
    for (int j = 0; j < 8; ++j) r[j] = f2bf(src[(size_t)(kbase + j) * 256]);
    uint4 o;
    o.x = (unsigned)r[0] | ((unsigned)r[1] << 16);
    o.y = (unsigned)r[2] | ((unsigned)r[3] << 16);
    o.z = (unsigned)r[4] | ((unsigned)r[5] << 16);
    o.w = (unsigned)r[6] | ((unsigned)r[7] << 16);
    *(uint4*)(wkv + (size_t)tid * 8) = o;
}

// ---------------- Q projection + RMSNorm ----------------
__global__ __launch_bounds__(256) void qproj_kernel(
    const float* __restrict__ agent, const float* __restrict__ Wq,
    const float* __restrict__ q_gamma, float* __restrict__ ws_q)
{
    __shared__ float srows[8][1024];
    int cg = blockIdx.x, rg = blockIdx.y;
    int t = threadIdx.x;
#pragma unroll
    for (int j = 0; j < 8; ++j) {
        int f = j * 256 + t;
        int row = f >> 8, c4 = f & 255;
        *(float4*)&srows[row][c4 * 4] =
            *(const float4*)(agent + (size_t)(rg * 8 + row) * 1024 + c4 * 4);
    }
    __syncthreads();
    int c = cg * 64 + (t & 63);
    int rq = t >> 6;
    float acc0 = 0.f, acc1 = 0.f;
    for (int k = 0; k < 1024; k += 4) {
        float w0 = Wq[(size_t)(k + 0) * 1024 + c];
        float w1 = Wq[(size_t)(k + 1) * 1024 + c];
        float w2 = Wq[(size_t)(k + 2) * 1024 + c];
        float w3 = Wq[(size_t)(k + 3) * 1024 + c];
        float4 a0 = *(const float4*)&srows[rq * 2][k];
        float4 a1 = *(const float4*)&srows[rq * 2 + 1][k];
        acc0 += a0.x * w0 + a0.y * w1 + a0.z * w2 + a0.w * w3;
        acc1 += a1.x * w0 + a1.y * w1 + a1.z * w2 + a1.w * w3;
    }
    float g = q_gamma[t & 63];
    float ss0 = acc0 * acc0, ss1 = acc1 * acc1;
#pragma unroll
    for (int d = 1; d < 64; d <<= 1) { ss0 += __shfl_xor(ss0, d); ss1 += __shfl_xor(ss1, d); }
    float rs0 = rsqrtf(ss0 * (1.0f / 64.0f) + EPS_);
    float rs1 = rsqrtf(ss1 * (1.0f / 64.0f) + EPS_);
    ws_q[(size_t)(rg * 8 + rq * 2 + 0) * 1024 + c] = acc0 * rs0 * g;
    ws_q[(size_t)(rg * 8 + rq * 2 + 1) * 1024 + c] = acc1 * rs1 * g;
}

// ---------------- Fused KV projection + attention (in-wave K+V) ----------------
// grid 512 = bt, 256 thr = 4 waves; wave = kv-head. Each wave computes K scores AND
// V rows for its head across 8 sub-chunks of 32 s-rows (acc[2][8]); softcap => plain
// sum softmax; no cross-wave combine. (256,3): ~170-reg cap, 3 blocks/CU.
__global__ __launch_bounds__(256, 3) void kv_attn_kernel(
    const float* __restrict__ z, const unsigned short* __restrict__ wkv,
    const float* __restrict__ ws_q, const float* __restrict__ k_gamma,
    float* __restrict__ ws_att)
{
    __shared__ __align__(16) unsigned short zlds[32 * 256];   // 16 KB, XOR-swizzled bf16
    const int bt = blockIdx.x;
    const int tid = threadIdx.x;
    const int head = tid >> 6;             // wave = kv head 0..3
    const int l = tid & 63, l15 = l & 15, lg = l >> 4;

    float qn[4][4], kgm[4];
#pragma unroll
    for (int g = 0; g < 4; ++g)
#pragma unroll
        for (int ni = 0; ni < 4; ++ni)
            qn[g][ni] = ws_q[(size_t)bt * 1024 + (head * 4 + g) * 64 + ni * 16 + l15];
#pragma unroll
    for (int ni = 0; ni < 4; ++ni) kgm[ni] = k_gamma[ni * 16 + l15];

    float out_acc[4][4] = {};
    float denom[4] = {};

    for (int sc = 0; sc < 8; ++sc) {       // 8 sub-chunks of 32 s-rows
        f32x4 acc[2][8];
#pragma unroll
        for (int mi = 0; mi < 2; ++mi)
#pragma unroll
            for (int ni = 0; ni < 8; ++ni) acc[mi][ni] = (f32x4){0.f, 0.f, 0.f, 0.f};

        for (int sl = 0; sl < 4; ++sl) {   // k-slices of 256
            __syncthreads();               // prior reads of zlds done
#pragma unroll
            for (int jb = 0; jb < 2; ++jb) {   // stage 32x256 fp32 -> bf16 (8 float4/thr)
                float4 v[4];
#pragma unroll
                for (int i = 0; i < 4; ++i) {
                    int f = (jb * 4 + i) * 256 + tid;   // float4 idx 0..2047
                    int row = f >> 6, c4 = f & 63;
                    v[i] = *(const float4*)(z + (size_t)(bt * 256 + sc * 32 + row) * 1024
                                              + sl * 256 + c4 * 4);
                }
#pragma unroll
                for (int i = 0; i < 4; ++i) {
                    int f = (jb * 4 + i) * 256 + tid;
                    int row = f >> 6, c4 = f & 63;
                    unsigned lo = (unsigned)f2bf(v[i].x) | ((unsigned)f2bf(v[i].y) << 16);
                    unsigned hi = (unsigned)f2bf(v[i].z) | ((unsigned)f2bf(v[i].w) << 16);
                    int byteoff = ((row * 512) + c4 * 8) ^ ((row & 7) << 4);
                    *(uint2*)((char*)zlds + byteoff) = (uint2){lo, hi};
                }
            }
            __syncthreads();               // stage visible
#pragma unroll
            for (int ksl = 0; ksl < 8; ++ksl) {
                const int kb = sl * 8 + ksl;
                int boff0 = ((l15 * 512) + ksl * 64 + lg * 16) ^ ((l15 & 7) << 4);
                bf16x8 a0 = *(const bf16x8*)((const char*)zlds + boff0);
                bf16x8 a1 = *(const bf16x8*)((const char*)zlds + boff0 + 8192); // row+16: same swizzle
                bf16x8 b[8];
#pragma unroll
                for (int ni = 0; ni < 8; ++ni) {
                    int nb = (ni < 4) ? (head * 4 + ni) : (16 + head * 4 + ni - 4);
                    b[ni] = *(const bf16x8*)(wkv + ((size_t)(kb * 32 + nb) * 64 + l) * 8);
                }
#pragma unroll
                for (int ni = 0; ni < 8; ++ni) {
                    acc[0][ni] = __builtin_amdgcn_mfma_f32_16x16x32_bf16(a0, b[ni], acc[0][ni], 0, 0, 0);
                    acc[1][ni] = __builtin_amdgcn_mfma_f32_16x16x32_bf16(a1, b[ni], acc[1][ni], 0, 0, 0);
                }
            }
        }
        // ---- in-wave attention epilogue for this sub-chunk's 32 rows (r6-proven) ----
#pragma unroll
        for (int mi = 0; mi < 2; ++mi) {
#pragma unroll
            for (int r = 0; r < 4; ++r) {
                float k0 = acc[mi][0][r], k1 = acc[mi][1][r], k2 = acc[mi][2][r], k3 = acc[mi][3][r];
                float ss = k0 * k0 + k1 * k1 + k2 * k2 + k3 * k3;
                ss += __shfl_xor(ss, 1); ss += __shfl_xor(ss, 2);
                ss += __shfl_xor(ss, 4); ss += __shfl_xor(ss, 8);
                float rs = rsqrtf(ss * (1.0f / 64.0f) + EPS_);
                k0 *= rs * kgm[0]; k1 *= rs * kgm[1]; k2 *= rs * kgm[2]; k3 *= rs * kgm[3];
#pragma unroll
                for (int g = 0; g < 4; ++g) {
                    float sp = qn[g][0] * k0 + qn[g][1] * k1 + qn[g][2] * k2 + qn[g][3] * k3;
                    sp += __shfl_xor(sp, 1); sp += __shfl_xor(sp, 2);
                    sp += __shfl_xor(sp, 4); sp += __shfl_xor(sp, 8);
                    float scv = sp * 0.125f;                    // * hd^-0.5
                    float e2 = __expf(scv * (2.0f / SOFTCAP_));
                    float th = 1.0f - 2.0f / (e2 + 1.0f);       // tanh
                    float p = __expf(SOFTCAP_ * th);            // |capped|<=50, fp32-safe
                    denom[g] += p;
                    out_acc[g][0] += p * acc[mi][4][r];
                    out_acc[g][1] += p * acc[mi][5][r];
                    out_acc[g][2] += p * acc[mi][6][r];
                    out_acc[g][3] += p * acc[mi][7][r];
                }
            }
        }
    }
    // ---- finalize in-wave: reduce over lane-groups, normalize, write ----
#pragma unroll
    for (int g = 0; g < 4; ++g) {
        float d = denom[g];
        d += __shfl_xor(d, 16); d += __shfl_xor(d, 32);
        float inv = 1.0f / d;
#pragma unroll
        for (int ni = 0; ni < 4; ++ni) {
            float o = out_acc[g][ni];
            o += __shfl_xor(o, 16); o += __shfl_xor(o, 32);
            if (lg == 0)
                ws_att[(size_t)bt * 1024 + (head * 4 + g) * 64 + ni * 16 + l15] = o * inv;
        }
    }
}

// ---------------- Output projection ----------------
__global__ __launch_bounds__(256) void oproj_kernel(
    const float* __restrict__ att, const float* __restrict__ Wo,
    float* __restrict__ out)
{
    __shared__ float srows[8][1024];
    int cg = blockIdx.x, rg = blockIdx.y;
    int t = threadIdx.x;
#pragma unroll
    for (int j = 0; j < 8; ++j) {
        int f = j * 256 + t;
        int row = f >> 8, c4 = f & 255;
        *(float4*)&srows[row][c4 * 4] =
            *(const float4*)(att + (size_t)(rg * 8 + row) * 1024 + c4 * 4);
    }
    __syncthreads();
    int c = cg * 64 + (t & 63);
    int rq = t >> 6;
    float acc0 = 0.f, acc1 = 0.f;
    for (int k = 0; k < 1024; k += 4) {
        float w0 = Wo[(size_t)(k + 0) * 1024 + c];
        float w1 = Wo[(size_t)(k + 1) * 1024 + c];
        float w2 = Wo[(size_t)(k + 2) * 1024 + c];
        float w3 = Wo[(size_t)(k + 3) * 1024 + c];
        float4 a0 = *(const float4*)&srows[rq * 2][k];
        float4 a1 = *(const float4*)&srows[rq * 2 + 1][k];
        acc0 += a0.x * w0 + a0.y * w1 + a0.z * w2 + a0.w * w3;
        acc1 += a1.x * w0 + a1.y * w1 + a1.z * w2 + a1.w * w3;
    }
    out[(size_t)(rg * 8 + rq * 2 + 0) * 1024 + c] = acc0;
    out[(size_t)(rg * 8 + rq * 2 + 1) * 1024 + c] = acc1;
}

extern "C" void kernel_launch(void* const* d_in, const int* in_sizes, int n_in,
                              void* d_out, int out_size, void* d_ws, size_t ws_size,
                              hipStream_t stream) {
    const float* agent = (const float*)d_in[0];
    const float* z     = (const float*)d_in[1];
    const float* Wq    = (const float*)d_in[2];
    const float* Wk    = (const float*)d_in[3];
    const float* Wv    = (const float*)d_in[4];
    const float* Wo    = (const float*)d_in[5];
    const float* qg    = (const float*)d_in[6];
    const float* kg    = (const float*)d_in[7];
    float* out = (float*)d_out;

    char* ws = (char*)d_ws;
    float* ws_q   = (float*)ws;                          // 2 MB
    float* ws_att = (float*)(ws + (2u << 20));           // 2 MB
    unsigned short* ws_wkv = (unsigned short*)(ws + (4u << 20)); // 1 MB  (5 MB total, proven)

    hipLaunchKernelGGL(wkv_swizzle, dim3(256), dim3(256), 0, stream, Wk, Wv, ws_wkv);
    hipLaunchKernelGGL(qproj_kernel, dim3(16, 64), dim3(256), 0, stream, agent, Wq, qg, ws_q);
    hipLaunchKernelGGL(kv_attn_kernel, dim3(512), dim3(256), 0, stream, z, ws_wkv, ws_q, kg, ws_att);
    hipLaunchKernelGGL(oproj_kernel, dim3(16, 64), dim3(256), 0, stream, ws_att, Wo, out);
}